// Round 1
// baseline (1110.030 us; speedup 1.0000x reference)
//
#include <hip/hip_runtime.h>
#include <hip/hip_bf16.h>
#include <math.h>

// Problem constants (from reference): B=2, S=2048, D=1024, H=16, dk=64
#define BATCH   2
#define SEQ     2048
#define DMODEL  1024
#define NHEAD   16
#define DK      64
#define MTOK    (BATCH*SEQ)     // 4096
#define QKVN    (3*DMODEL)      // 3072

// ---------------- SGEMM: C[M,N] = A[M,K] * B[N,K]^T (both row-major) --------
#define BM 128
#define BN 128
#define BK 16
#define TM 8
#define TN 8

__global__ __launch_bounds__(256) void gemm_nt(const float* __restrict__ A,
                                               const float* __restrict__ B,
                                               float* __restrict__ C,
                                               int M, int N, int K) {
    __shared__ float As[BK][BM + 4];   // stride 132 floats = 33*16B, float4-aligned rows
    __shared__ float Bs[BK][BN + 4];
    const int tid = threadIdx.x;
    const int m0 = blockIdx.y * BM;
    const int n0 = blockIdx.x * BN;
    const int tm = (tid / 16) * TM;
    const int tn = (tid % 16) * TN;

    float acc[TM][TN];
#pragma unroll
    for (int i = 0; i < TM; i++)
#pragma unroll
        for (int j = 0; j < TN; j++) acc[i][j] = 0.f;

    for (int k0 = 0; k0 < K; k0 += BK) {
        // A tile: 128x16 = 512 float4, 2 per thread; store transposed As[k][m]
#pragma unroll
        for (int i = 0; i < 2; i++) {
            int f4  = tid + i * 256;          // 0..511
            int row = f4 >> 2;                // 0..127
            int kc  = (f4 & 3) * 4;           // 0,4,8,12
            float4 v = *(const float4*)&A[(size_t)(m0 + row) * K + k0 + kc];
            As[kc + 0][row] = v.x; As[kc + 1][row] = v.y;
            As[kc + 2][row] = v.z; As[kc + 3][row] = v.w;
        }
#pragma unroll
        for (int i = 0; i < 2; i++) {
            int f4  = tid + i * 256;
            int row = f4 >> 2;
            int kc  = (f4 & 3) * 4;
            float4 v = *(const float4*)&B[(size_t)(n0 + row) * K + k0 + kc];
            Bs[kc + 0][row] = v.x; Bs[kc + 1][row] = v.y;
            Bs[kc + 2][row] = v.z; Bs[kc + 3][row] = v.w;
        }
        __syncthreads();
#pragma unroll
        for (int kk = 0; kk < BK; kk++) {
            const float4* ap = (const float4*)&As[kk][tm];
            const float4* bp = (const float4*)&Bs[kk][tn];
            float4 a0 = ap[0], a1 = ap[1];
            float4 b0 = bp[0], b1 = bp[1];
            float a[TM] = {a0.x, a0.y, a0.z, a0.w, a1.x, a1.y, a1.z, a1.w};
            float b[TN] = {b0.x, b0.y, b0.z, b0.w, b1.x, b1.y, b1.z, b1.w};
#pragma unroll
            for (int i = 0; i < TM; i++)
#pragma unroll
                for (int j = 0; j < TN; j++)
                    acc[i][j] = fmaf(a[i], b[j], acc[i][j]);
        }
        __syncthreads();
    }
#pragma unroll
    for (int i = 0; i < TM; i++) {
        float4* cp = (float4*)&C[(size_t)(m0 + tm + i) * N + n0 + tn];
        cp[0] = make_float4(acc[i][0], acc[i][1], acc[i][2], acc[i][3]);
        cp[1] = make_float4(acc[i][4], acc[i][5], acc[i][6], acc[i][7]);
    }
}

// ---------------- RoPE in-place on q,k halves of qkv ------------------------
// qkv: [MTOK][3072]; q = cols [0,1024), k = cols [1024,2048).
// Per head (dk=64): out[2j]   = x1*cos - x2*sin,  out[2j+1] = x1*sin + x2*cos
// ang = pos * 10000^(-j/32), pos = row % S.
__global__ void rope_kernel(float* __restrict__ qkv) {
    int idx = blockIdx.x * blockDim.x + threadIdx.x;   // one thread per (row, pair)
    if (idx >= MTOK * 1024) return;                    // 512 q-pairs + 512 k-pairs per row
    int row  = idx >> 10;
    int p    = idx & 1023;
    int half = p >> 9;              // 0=q, 1=k
    int pp   = p & 511;
    int hh   = pp >> 5;             // head
    int j    = pp & 31;             // pair index within head
    int col  = half * DMODEL + hh * DK + 2 * j;
    int s    = row & (SEQ - 1);
    // inv_freq = 2^(-j * log2(10000)/32)
    float inv = exp2f(-(float)j * 0.41524101186092030f);
    float ang = (float)s * inv;
    float sn, cs;
    sincosf(ang, &sn, &cs);
    float* base = qkv + (size_t)row * QKVN + col;
    float x1 = base[0], x2 = base[1];
    base[0] = x1 * cs - x2 * sn;
    base[1] = x1 * sn + x2 * cs;
}

// ---------------- Causal flash attention (fp32) -----------------------------
// One block per (q-tile of 64, head, batch). 256 threads: thread = (qr, cg),
// qr = tid/4 (q-row 0..63), cg = tid&3 owns output cols cg*16..+15.
#define QT 64
#define KT 64

__global__ __launch_bounds__(256) void attn_kernel(const float* __restrict__ qkv,
                                                   float* __restrict__ out /*[MTOK][DMODEL] merged*/) {
    __shared__ float Qs [QT][DK + 4];
    __shared__ float KsT[DK][KT + 4];
    __shared__ float Vs [KT][DK + 4];
    __shared__ float Ps [QT][KT + 4];

    const int qt  = blockIdx.x;    // 0..31
    const int h   = blockIdx.y;    // 0..15
    const int b   = blockIdx.z;    // 0..1
    const int tid = threadIdx.x;
    const int qr  = tid >> 2;      // 0..63
    const int cg  = tid & 3;       // 0..3
    const float scale = 0.125f;    // 1/sqrt(64)

    const float* qbase = qkv + (size_t)b * SEQ * QKVN + (size_t)h * DK;
    const float* kbase = qbase + DMODEL;
    const float* vbase = qbase + 2 * DMODEL;

    // Load Q tile (pre-scaled): 64x64 = 1024 float4, 4 per thread
#pragma unroll
    for (int i = 0; i < 4; i++) {
        int f4  = tid + i * 256;
        int row = f4 >> 4;             // 0..63
        int dc  = (f4 & 15) * 4;       // 0..60
        float4 v = *(const float4*)&qbase[(size_t)(qt * QT + row) * QKVN + dc];
        Qs[row][dc + 0] = v.x * scale; Qs[row][dc + 1] = v.y * scale;
        Qs[row][dc + 2] = v.z * scale; Qs[row][dc + 3] = v.w * scale;
    }

    float m = -INFINITY, l = 0.f;
    float o[16];
#pragma unroll
    for (int j = 0; j < 16; j++) o[j] = 0.f;

    for (int kt = 0; kt <= qt; kt++) {
        __syncthreads();   // previous iteration's reads of KsT/Vs/Ps are done
        // Load K tile (transposed) and V tile
#pragma unroll
        for (int i = 0; i < 4; i++) {
            int f4  = tid + i * 256;
            int row = f4 >> 4;
            int dc  = (f4 & 15) * 4;
            float4 kv = *(const float4*)&kbase[(size_t)(kt * KT + row) * QKVN + dc];
            KsT[dc + 0][row] = kv.x; KsT[dc + 1][row] = kv.y;
            KsT[dc + 2][row] = kv.z; KsT[dc + 3][row] = kv.w;
            float4 vv = *(const float4*)&vbase[(size_t)(kt * KT + row) * QKVN + dc];
            *(float4*)&Vs[row][dc] = vv;
        }
        __syncthreads();

        // Scores: 16 keys per thread (keys cg*16 .. cg*16+15)
        float s[16];
#pragma unroll
        for (int kk = 0; kk < 16; kk++) s[kk] = 0.f;
        for (int d = 0; d < DK; d++) {
            float qv = Qs[qr][d];
            const float* kp = &KsT[d][cg * 16];
            float4 k0 = *(const float4*)(kp + 0);
            float4 k1 = *(const float4*)(kp + 4);
            float4 k2 = *(const float4*)(kp + 8);
            float4 k3 = *(const float4*)(kp + 12);
            s[0]  = fmaf(qv, k0.x, s[0]);  s[1]  = fmaf(qv, k0.y, s[1]);
            s[2]  = fmaf(qv, k0.z, s[2]);  s[3]  = fmaf(qv, k0.w, s[3]);
            s[4]  = fmaf(qv, k1.x, s[4]);  s[5]  = fmaf(qv, k1.y, s[5]);
            s[6]  = fmaf(qv, k1.z, s[6]);  s[7]  = fmaf(qv, k1.w, s[7]);
            s[8]  = fmaf(qv, k2.x, s[8]);  s[9]  = fmaf(qv, k2.y, s[9]);
            s[10] = fmaf(qv, k2.z, s[10]); s[11] = fmaf(qv, k2.w, s[11]);
            s[12] = fmaf(qv, k3.x, s[12]); s[13] = fmaf(qv, k3.y, s[13]);
            s[14] = fmaf(qv, k3.z, s[14]); s[15] = fmaf(qv, k3.w, s[15]);
        }
        if (kt == qt) {   // causal mask on diagonal tile (local indices suffice)
#pragma unroll
            for (int kk = 0; kk < 16; kk++)
                if (cg * 16 + kk > qr) s[kk] = -INFINITY;
        }

        // Row reduce (16 regs, then across the 4 cg lanes of this q-row)
        float mt = s[0];
#pragma unroll
        for (int kk = 1; kk < 16; kk++) mt = fmaxf(mt, s[kk]);
        mt = fmaxf(mt, __shfl_xor(mt, 1));
        mt = fmaxf(mt, __shfl_xor(mt, 2));
        float mnew = fmaxf(m, mt);           // finite after first tile of every row
        float corr = __expf(m - mnew);       // m=-inf initially -> corr=0

        float ls = 0.f;
#pragma unroll
        for (int kk = 0; kk < 16; kk++) {
            float p = __expf(s[kk] - mnew);  // masked -> exp(-inf)=0
            ls += p;
            Ps[qr][cg * 16 + kk] = p;
        }
        ls += __shfl_xor(ls, 1);
        ls += __shfl_xor(ls, 2);
        l = l * corr + ls;
#pragma unroll
        for (int j = 0; j < 16; j++) o[j] *= corr;
        m = mnew;
        __syncthreads();   // Ps fully written before PV

        // PV: o[qr][cg*16+j] += sum_key Ps[qr][key] * Vs[key][cg*16+j]
        for (int key = 0; key < KT; key++) {
            float pv = Ps[qr][key];
            const float* vp = &Vs[key][cg * 16];
            float4 v0 = *(const float4*)(vp + 0);
            float4 v1 = *(const float4*)(vp + 4);
            float4 v2 = *(const float4*)(vp + 8);
            float4 v3 = *(const float4*)(vp + 12);
            o[0]  = fmaf(pv, v0.x, o[0]);  o[1]  = fmaf(pv, v0.y, o[1]);
            o[2]  = fmaf(pv, v0.z, o[2]);  o[3]  = fmaf(pv, v0.w, o[3]);
            o[4]  = fmaf(pv, v1.x, o[4]);  o[5]  = fmaf(pv, v1.y, o[5]);
            o[6]  = fmaf(pv, v1.z, o[6]);  o[7]  = fmaf(pv, v1.w, o[7]);
            o[8]  = fmaf(pv, v2.x, o[8]);  o[9]  = fmaf(pv, v2.y, o[9]);
            o[10] = fmaf(pv, v2.z, o[10]); o[11] = fmaf(pv, v2.w, o[11]);
            o[12] = fmaf(pv, v3.x, o[12]); o[13] = fmaf(pv, v3.y, o[13]);
            o[14] = fmaf(pv, v3.z, o[14]); o[15] = fmaf(pv, v3.w, o[15]);
        }
    }

    // Normalize and store in merged (B,S,D) layout: col = h*64 + cg*16 + j
    float inv_l = 1.0f / l;
    float* obase = out + (size_t)(b * SEQ + qt * QT + qr) * DMODEL + h * DK + cg * 16;
#pragma unroll
    for (int g = 0; g < 4; g++) {
        *(float4*)&obase[g * 4] = make_float4(o[g*4+0] * inv_l, o[g*4+1] * inv_l,
                                              o[g*4+2] * inv_l, o[g*4+3] * inv_l);
    }
}

// ---------------- launch ----------------------------------------------------
extern "C" void kernel_launch(void* const* d_in, const int* in_sizes, int n_in,
                              void* d_out, int out_size, void* d_ws, size_t ws_size,
                              hipStream_t stream) {
    const float* x    = (const float*)d_in[0];   // [2,2048,1024]
    const float* Wqkv = (const float*)d_in[1];   // [3072,1024]
    const float* Wout = (const float*)d_in[2];   // [1024,1024]
    float* out = (float*)d_out;                  // [2,2048,1024]

    // workspace: qkv [4096][3072] (48MB) + merged heads [4096][1024] (16MB)
    float* qkv    = (float*)d_ws;
    float* merged = (float*)((char*)d_ws + (size_t)MTOK * QKVN * sizeof(float));

    // 1) qkv = x @ Wqkv^T
    dim3 g1(QKVN / BN, MTOK / BM);   // (24, 32)
    gemm_nt<<<g1, 256, 0, stream>>>(x, Wqkv, qkv, MTOK, QKVN, DMODEL);

    // 2) RoPE in place on q,k
    int tot = MTOK * 1024;
    rope_kernel<<<(tot + 255) / 256, 256, 0, stream>>>(qkv);

    // 3) causal attention -> merged
    dim3 g2(SEQ / QT, NHEAD, BATCH); // (32, 16, 2)
    attn_kernel<<<g2, 256, 0, stream>>>(qkv, merged);

    // 4) out = merged @ Wout^T
    dim3 g3(DMODEL / BN, MTOK / BM); // (8, 32)
    gemm_nt<<<g3, 256, 0, stream>>>(merged, Wout, out, MTOK, DMODEL, DMODEL);
}

// Round 2
// 262.967 us; speedup vs baseline: 4.2212x; 4.2212x over previous
//
#include <hip/hip_runtime.h>
#include <hip/hip_bf16.h>
#include <math.h>

#define BATCH   2
#define SEQ     2048
#define DMODEL  1024
#define NHEAD   16
#define DK      64
#define MTOK    (BATCH*SEQ)     // 4096
#define QKVN    (3*DMODEL)      // 3072
#define BH      (BATCH*NHEAD)   // 32

typedef __attribute__((ext_vector_type(8))) __bf16 bf16x8;
typedef __attribute__((ext_vector_type(4))) float  f32x4;

#define GL16(gp, lp) __builtin_amdgcn_global_load_lds( \
    (const __attribute__((address_space(1))) unsigned int*)(gp), \
    (__attribute__((address_space(3))) unsigned int*)(lp), 16, 0, 0)

// ---------------- fp32 -> bf16 convert --------------------------------------
__global__ __launch_bounds__(256) void cvt_bf16(const float* __restrict__ in,
                                                __hip_bfloat16* __restrict__ out, int n) {
    int i = (blockIdx.x * 256 + threadIdx.x) * 4;
    if (i >= n) return;
    float4 v = *(const float4*)(in + i);
    __hip_bfloat162 a, b;
    a.x = __float2bfloat16(v.x); a.y = __float2bfloat16(v.y);
    b.x = __float2bfloat16(v.z); b.y = __float2bfloat16(v.w);
    *(__hip_bfloat162*)(out + i)     = a;
    *(__hip_bfloat162*)(out + i + 2) = b;
}

// ---------------- bf16 MFMA GEMM (NT): C[M,N] = A[M,K] * B[N,K]^T ----------
// m97 structure: 128x128 tile, BK=32, 4 waves (2x2), global_load_lds w=16.
#define GBM 128
#define GBN 128
#define GBK 32

template<int OUT_BF16>
__global__ __launch_bounds__(256) void gemm_bf16_nt(const __hip_bfloat16* __restrict__ A,
                                                    const __hip_bfloat16* __restrict__ B,
                                                    void* __restrict__ Cv,
                                                    int M, int N, int K) {
    __shared__ __align__(16) __hip_bfloat16 As[GBM][GBK];   // 8 KB, linear
    __shared__ __align__(16) __hip_bfloat16 Bs[GBN][GBK];   // 8 KB
    const int tid  = threadIdx.x;
    const int wid  = tid >> 6;
    const int lane = tid & 63;
    const int fr   = lane & 15;     // fragment row/col
    const int fq   = lane >> 4;     // k-chunk / row-quad
    const int wm   = (wid >> 1) * 64;
    const int wn   = (wid & 1) * 64;
    const int m0   = blockIdx.y * GBM;
    const int n0   = blockIdx.x * GBN;

    f32x4 acc[4][4];
#pragma unroll
    for (int m = 0; m < 4; m++)
#pragma unroll
        for (int n = 0; n < 4; n++) acc[m][n] = (f32x4)0.f;

    // staging: chunk c (16B) -> row c/4, koff (c&3)*8; thread owns chunks tid, tid+256
    const __hip_bfloat16* a0 = A + (size_t)(m0 + (tid >> 2)) * K + (tid & 3) * 8;
    const __hip_bfloat16* a1 = a0 + (size_t)64 * K;
    const __hip_bfloat16* b0 = B + (size_t)(n0 + (tid >> 2)) * K + (tid & 3) * 8;
    const __hip_bfloat16* b1 = b0 + (size_t)64 * K;
    __hip_bfloat16* asd0 = &As[0][0] + tid * 8;
    __hip_bfloat16* asd1 = asd0 + 2048;
    __hip_bfloat16* bsd0 = &Bs[0][0] + tid * 8;
    __hip_bfloat16* bsd1 = bsd0 + 2048;

    const __hip_bfloat16* ArP = &As[wm + fr][0] + fq * 8;
    const __hip_bfloat16* BrP = &Bs[wn + fr][0] + fq * 8;

    for (int k0 = 0; k0 < K; k0 += GBK) {
        GL16(a0 + k0, asd0);
        GL16(a1 + k0, asd1);
        GL16(b0 + k0, bsd0);
        GL16(b1 + k0, bsd1);
        __syncthreads();    // drains vmcnt -> staging visible

        bf16x8 af[4], bfv[4];
#pragma unroll
        for (int m = 0; m < 4; m++) af[m]  = *(const bf16x8*)(ArP + m * 512);
#pragma unroll
        for (int n = 0; n < 4; n++) bfv[n] = *(const bf16x8*)(BrP + n * 512);
#pragma unroll
        for (int m = 0; m < 4; m++)
#pragma unroll
            for (int n = 0; n < 4; n++)
                acc[m][n] = __builtin_amdgcn_mfma_f32_16x16x32_bf16(af[m], bfv[n], acc[m][n], 0, 0, 0);
        __syncthreads();    // all reads done before next stage
    }

    // epilogue: C row = m0+wm+m*16+fq*4+r, col = n0+wn+n*16+fr
#pragma unroll
    for (int m = 0; m < 4; m++)
#pragma unroll
        for (int n = 0; n < 4; n++)
#pragma unroll
            for (int r = 0; r < 4; r++) {
                size_t row = m0 + wm + m * 16 + fq * 4 + r;
                size_t col = n0 + wn + n * 16 + fr;
                if (OUT_BF16)
                    ((__hip_bfloat16*)Cv)[row * N + col] = __float2bfloat16(acc[m][n][r]);
                else
                    ((float*)Cv)[row * N + col] = acc[m][n][r];
            }
}

// ---------------- RoPE + head-major repack of q,k ---------------------------
__global__ __launch_bounds__(256) void rope_qk(const __hip_bfloat16* __restrict__ qkvb,
                                               __hip_bfloat16* __restrict__ qh,
                                               __hip_bfloat16* __restrict__ kh) {
    int idx  = blockIdx.x * 256 + threadIdx.x;   // MTOK*1024 threads
    int row  = idx >> 10;
    int p    = idx & 1023;
    int half = p >> 9;             // 0=q, 1=k
    int pp   = p & 511;
    int hh   = pp >> 5;            // head
    int j    = pp & 31;            // pair
    int b    = row >> 11, s = row & (SEQ - 1);
    const __hip_bfloat16* src = qkvb + (size_t)row * QKVN + half * DMODEL + hh * DK + 2 * j;
    __hip_bfloat162 xv = *(const __hip_bfloat162*)src;
    float x1 = __bfloat162float(xv.x);
    float x2 = __bfloat162float(xv.y);
    float inv = exp2f(-(float)j * 0.41524101186092030f);   // 10000^(-j/32)
    float ang = (float)s * inv;
    float sn, cs;
    sincosf(ang, &sn, &cs);
    __hip_bfloat162 o;
    o.x = __float2bfloat16(x1 * cs - x2 * sn);
    o.y = __float2bfloat16(x1 * sn + x2 * cs);
    __hip_bfloat16* dst = (half ? kh : qh) + ((size_t)(b * NHEAD + hh) * SEQ + s) * DK + 2 * j;
    *(__hip_bfloat162*)dst = o;
}

// ---------------- V transpose: vt[bh][d][s] = v[b][s][h*64+d] ---------------
__global__ __launch_bounds__(256) void v_trans(const __hip_bfloat16* __restrict__ qkvb,
                                               __hip_bfloat16* __restrict__ vt) {
    const int t  = threadIdx.x;
    const int s  = blockIdx.x * 256 + t;
    const int bh = blockIdx.y;
    const int b  = bh >> 4, h = bh & 15;
    const __hip_bfloat16* src = qkvb + (size_t)(b * SEQ + s) * QKVN + 2 * DMODEL + h * DK;
    __hip_bfloat16* dst = vt + (size_t)bh * DK * SEQ + s;
#pragma unroll
    for (int d2 = 0; d2 < 32; d2++) {
        __hip_bfloat162 v = *(const __hip_bfloat162*)(src + 2 * d2);
        dst[(size_t)(2 * d2) * SEQ]     = v.x;
        dst[(size_t)(2 * d2 + 1) * SEQ] = v.y;
    }
}

// ---------------- MFMA flash attention (causal) -----------------------------
// Block = (q-tile of 128, bh). 4 waves, each owns 32 q-rows, fully independent.
// K-tiles of 64 keys; QK^T and PV via mfma_f32_16x16x32_bf16; P staged through
// a per-wave XOR-swizzled LDS slab.
__global__ __launch_bounds__(256) void attn_mfma(const __hip_bfloat16* __restrict__ qh,
                                                 const __hip_bfloat16* __restrict__ kh,
                                                 const __hip_bfloat16* __restrict__ vt,
                                                 __hip_bfloat16* __restrict__ mergedb) {
    __shared__ __align__(16) __hip_bfloat16 Ps[4][2048];   // 4 KB per wave
    const int tid = threadIdx.x, wid = tid >> 6, lane = tid & 63;
    const int fr = lane & 15, fq = lane >> 4;
    const int bid = blockIdx.x;                 // 512 blocks
    const int qt  = 15 - (bid >> 5);            // heavy tiles dispatched first
    const int bh  = bid & 31;
    const int b   = bh >> 4, h = bh & 15;

    const size_t hoff = (size_t)bh * SEQ * DK;
    const __hip_bfloat16* Qb = qh + hoff;
    const __hip_bfloat16* Kb = kh + hoff;
    const __hip_bfloat16* Vb = vt + hoff;       // [64][SEQ]

    const int q0 = qt * 128 + wid * 32;         // wave's first global q-row

    bf16x8 qf[2][2];
#pragma unroll
    for (int m = 0; m < 2; m++)
#pragma unroll
        for (int c = 0; c < 2; c++)
            qf[m][c] = *(const bf16x8*)&Qb[(size_t)(q0 + m * 16 + fr) * DK + c * 32 + fq * 8];

    f32x4 o[2][4];
#pragma unroll
    for (int m = 0; m < 2; m++)
#pragma unroll
        for (int n = 0; n < 4; n++) o[m][n] = (f32x4)0.f;
    float mrun[8], lrun[8];
#pragma unroll
    for (int i = 0; i < 8; i++) { mrun[i] = -INFINITY; lrun[i] = 0.f; }

    char* Pw = (char*)&Ps[wid][0];
    const int nkt = 2 * qt + 2;

    for (int kt = 0; kt < nkt; kt++) {
        const int key0 = kt * 64;
        // ---- S = Q K^T (fp32 acc)
        f32x4 s_acc[2][4];
#pragma unroll
        for (int m = 0; m < 2; m++)
#pragma unroll
            for (int n = 0; n < 4; n++) s_acc[m][n] = (f32x4)0.f;
#pragma unroll
        for (int n = 0; n < 4; n++) {
            bf16x8 k0f = *(const bf16x8*)&Kb[(size_t)(key0 + n * 16 + fr) * DK + fq * 8];
            bf16x8 k1f = *(const bf16x8*)&Kb[(size_t)(key0 + n * 16 + fr) * DK + 32 + fq * 8];
#pragma unroll
            for (int m = 0; m < 2; m++) {
                s_acc[m][n] = __builtin_amdgcn_mfma_f32_16x16x32_bf16(qf[m][0], k0f, s_acc[m][n], 0, 0, 0);
                s_acc[m][n] = __builtin_amdgcn_mfma_f32_16x16x32_bf16(qf[m][1], k1f, s_acc[m][n], 0, 0, 0);
            }
        }
        // ---- scale + causal mask
#pragma unroll
        for (int m = 0; m < 2; m++)
#pragma unroll
            for (int n = 0; n < 4; n++)
#pragma unroll
                for (int r = 0; r < 4; r++) s_acc[m][n][r] *= 0.125f;
        if (kt >= 2 * qt) {
#pragma unroll
            for (int m = 0; m < 2; m++)
#pragma unroll
                for (int n = 0; n < 4; n++)
#pragma unroll
                    for (int r = 0; r < 4; r++) {
                        int qrow = q0 + m * 16 + fq * 4 + r;
                        int key  = key0 + n * 16 + fr;
                        if (key > qrow) s_acc[m][n][r] = -INFINITY;
                    }
        }
        // ---- online softmax per row (rows live on 16-lane groups)
#pragma unroll
        for (int m = 0; m < 2; m++)
#pragma unroll
            for (int r = 0; r < 4; r++) {
                float mx = fmaxf(fmaxf(s_acc[m][0][r], s_acc[m][1][r]),
                                 fmaxf(s_acc[m][2][r], s_acc[m][3][r]));
                mx = fmaxf(mx, __shfl_xor(mx, 1));
                mx = fmaxf(mx, __shfl_xor(mx, 2));
                mx = fmaxf(mx, __shfl_xor(mx, 4));
                mx = fmaxf(mx, __shfl_xor(mx, 8));
                const int ri = m * 4 + r;
                float mnew = fmaxf(mrun[ri], mx);
                float corr = __expf(mrun[ri] - mnew);
                mrun[ri] = mnew;
                float rs = 0.f;
#pragma unroll
                for (int n = 0; n < 4; n++) {
                    float pv = __expf(s_acc[m][n][r] - mnew);
                    s_acc[m][n][r] = pv;
                    rs += pv;
                }
                rs += __shfl_xor(rs, 1);
                rs += __shfl_xor(rs, 2);
                rs += __shfl_xor(rs, 4);
                rs += __shfl_xor(rs, 8);
                lrun[ri] = lrun[ri] * corr + rs;
#pragma unroll
                for (int n = 0; n < 4; n++) o[m][n][r] *= corr;
            }
        // ---- P -> LDS (bf16, XOR-swizzled rows)
#pragma unroll
        for (int m = 0; m < 2; m++)
#pragma unroll
            for (int r = 0; r < 4; r++) {
                int rl = m * 16 + fq * 4 + r;
                int sw = (rl & 7) << 4;
#pragma unroll
                for (int n = 0; n < 4; n++) {
                    int key = n * 16 + fr;
                    *(__hip_bfloat16*)(Pw + (((rl << 7) + (key << 1)) ^ sw)) =
                        __float2bfloat16(s_acc[m][n][r]);
                }
            }
        asm volatile("s_waitcnt lgkmcnt(0)" ::: "memory");
        __builtin_amdgcn_sched_barrier(0);
        // ---- PV
        bf16x8 pa[2][2];
#pragma unroll
        for (int m = 0; m < 2; m++)
#pragma unroll
            for (int c = 0; c < 2; c++) {
                int rl = m * 16 + fr;
                pa[m][c] = *(const bf16x8*)(Pw + (((rl << 7) + ((c * 32 + fq * 8) << 1)) ^ ((rl & 7) << 4)));
            }
#pragma unroll
        for (int n = 0; n < 4; n++) {
            bf16x8 v0f = *(const bf16x8*)&Vb[(size_t)(n * 16 + fr) * SEQ + key0 + fq * 8];
            bf16x8 v1f = *(const bf16x8*)&Vb[(size_t)(n * 16 + fr) * SEQ + key0 + 32 + fq * 8];
#pragma unroll
            for (int m = 0; m < 2; m++) {
                o[m][n] = __builtin_amdgcn_mfma_f32_16x16x32_bf16(pa[m][0], v0f, o[m][n], 0, 0, 0);
                o[m][n] = __builtin_amdgcn_mfma_f32_16x16x32_bf16(pa[m][1], v1f, o[m][n], 0, 0, 0);
            }
        }
    }

    // ---- normalize + store merged bf16 [MTOK][DMODEL]
#pragma unroll
    for (int m = 0; m < 2; m++)
#pragma unroll
        for (int r = 0; r < 4; r++) {
            float invl = 1.0f / lrun[m * 4 + r];
            int qrow = q0 + m * 16 + fq * 4 + r;
#pragma unroll
            for (int n = 0; n < 4; n++) {
                int col = h * DK + n * 16 + fr;
                mergedb[(size_t)(b * SEQ + qrow) * DMODEL + col] =
                    __float2bfloat16(o[m][n][r] * invl);
            }
        }
}

// ---------------- launch ----------------------------------------------------
extern "C" void kernel_launch(void* const* d_in, const int* in_sizes, int n_in,
                              void* d_out, int out_size, void* d_ws, size_t ws_size,
                              hipStream_t stream) {
    const float* x    = (const float*)d_in[0];
    const float* Wqkv = (const float*)d_in[1];
    const float* Wout = (const float*)d_in[2];
    float* out = (float*)d_out;

    char* w = (char*)d_ws;
    __hip_bfloat16* qkvb   = (__hip_bfloat16*)(w);                       // 24 MB
    __hip_bfloat16* qh     = (__hip_bfloat16*)(w + (24u << 20));         //  8 MB
    __hip_bfloat16* kh     = (__hip_bfloat16*)(w + (32u << 20));         //  8 MB
    __hip_bfloat16* vt     = (__hip_bfloat16*)(w + (40u << 20));         //  8 MB
    __hip_bfloat16* xb     = (__hip_bfloat16*)(w + (48u << 20));         //  8 MB (reused)
    __hip_bfloat16* merged = (__hip_bfloat16*)(w + (48u << 20));         //  8 MB (after xb dead)
    __hip_bfloat16* wqkvb  = (__hip_bfloat16*)(w + (56u << 20));         //  6 MB
    __hip_bfloat16* woutb  = (__hip_bfloat16*)(w + (62u << 20));         //  2 MB

    // 1) convert inputs to bf16
    cvt_bf16<<<MTOK * DMODEL / 1024, 256, 0, stream>>>(x, xb, MTOK * DMODEL);
    cvt_bf16<<<QKVN * DMODEL / 1024, 256, 0, stream>>>(Wqkv, wqkvb, QKVN * DMODEL);
    cvt_bf16<<<DMODEL * DMODEL / 1024, 256, 0, stream>>>(Wout, woutb, DMODEL * DMODEL);

    // 2) qkv = x @ Wqkv^T  (bf16 out)
    dim3 g1(QKVN / GBN, MTOK / GBM);
    gemm_bf16_nt<1><<<g1, 256, 0, stream>>>(xb, wqkvb, qkvb, MTOK, QKVN, DMODEL);

    // 3) RoPE repack q,k head-major; transpose v
    rope_qk<<<MTOK * 1024 / 256, 256, 0, stream>>>(qkvb, qh, kh);
    v_trans<<<dim3(SEQ / 256, BH), 256, 0, stream>>>(qkvb, vt);

    // 4) causal MFMA flash attention -> merged bf16
    attn_mfma<<<512, 256, 0, stream>>>(qh, kh, vt, merged);

    // 5) out = merged @ Wout^T (fp32 out)
    dim3 g3(DMODEL / GBN, MTOK / GBM);
    gemm_bf16_nt<0><<<g3, 256, 0, stream>>>(merged, woutb, out, MTOK, DMODEL, DMODEL);
}